// Round 11
// baseline (302.278 us; speedup 1.0000x reference)
//
#include <hip/hip_runtime.h>
#include <math.h>

#define D 64
#define NB 1024           // row buckets
#define PA_T 256
#define PA_E 8
#define PA_EDGES (PA_T * PA_E)   // 2048 edges per binA block
#define PB_T 256
#define PB_CAP 2048       // staged edges per bucket (mean ~1221)
#define RPB_MAX 320       // max rows per bucket (actual 147 for N=150000)

// ---- bf16 pack/unpack (RNE) ----
__device__ __forceinline__ unsigned bfpack(float a, float b) {
  unsigned ua = __float_as_uint(a);
  unsigned ub = __float_as_uint(b);
  ua = (ua + 0x7FFFu + ((ua >> 16) & 1u)) >> 16;
  ub = (ub + 0x7FFFu + ((ub >> 16) & 1u)) >> 16;
  return (ua & 0xFFFFu) | (ub << 16);
}
__device__ __forceinline__ float bflo(unsigned u) { return __uint_as_float(u << 16); }
__device__ __forceinline__ float bfhi(unsigned u) { return __uint_as_float(u & 0xFFFF0000u); }
__device__ __forceinline__ float bf2f(unsigned short s) {
  return __uint_as_float(((unsigned)s) << 16);
}

__global__ void k_zero(int* __restrict__ a, int n) {
  int i = blockIdx.x * blockDim.x + threadIdx.x;
  if (i < n) a[i] = 0;
}

// per-block LDS bucket histogram -> few global atomics
__global__ void k_bhist(const int* __restrict__ erow, int* __restrict__ bhist,
                        int E, int RPB) {
  __shared__ int h[NB];
  int t = threadIdx.x;
  for (int i = t; i < NB; i += PA_T) h[i] = 0;
  __syncthreads();
  int base = blockIdx.x * PA_EDGES;
  #pragma unroll
  for (int j = 0; j < PA_E; ++j) {
    int e = base + t + j * PA_T;
    if (e < E) atomicAdd(&h[erow[e] / RPB], 1);
  }
  __syncthreads();
  for (int i = t; i < NB; i += PA_T) if (h[i] > 0) atomicAdd(&bhist[i], h[i]);
}

// exclusive scan of NB bucket counts -> bbase[NB+1] (single block, 256 threads)
__global__ void k_bscan(const int* __restrict__ bhist, int* __restrict__ bbase, int E) {
  __shared__ int sums[PA_T];
  const int C = NB / PA_T;   // 4
  int t = threadIdx.x;
  int lo = t * C;
  int v[C];
  int s = 0;
  #pragma unroll
  for (int i = 0; i < C; ++i) { v[i] = bhist[lo + i]; s += v[i]; }
  sums[t] = s;
  __syncthreads();
  for (int off = 1; off < PA_T; off <<= 1) {
    int x = (t >= off) ? sums[t - off] : 0;
    __syncthreads();
    sums[t] += x;
    __syncthreads();
  }
  int run = sums[t] - s;
  #pragma unroll
  for (int i = 0; i < C; ++i) { bbase[lo + i] = run; run += v[i]; }
  if (t == PA_T - 1) bbase[NB] = E;
}

// pass A: block-local counting sort by bucket, chunk-reserved coalesced writes
__global__ void k_binA(const int* __restrict__ erow, const int* __restrict__ ecol,
                       const float* __restrict__ eval, const int* __restrict__ bbase,
                       int* __restrict__ bfill, int4* __restrict__ binned,
                       int E, int RPB) {
  __shared__ int h[NB];
  __shared__ int lstart[NB];
  __shared__ int cbase[NB];
  __shared__ int lfill[NB];
  __shared__ int csum[PA_T];
  __shared__ int4 stage[PA_EDGES];
  __shared__ int sdest[PA_EDGES];
  const int C = NB / PA_T;   // 4
  int t = threadIdx.x;
  int base = blockIdx.x * PA_EDGES;
  for (int i = t; i < NB; i += PA_T) { h[i] = 0; lfill[i] = 0; }
  __syncthreads();
  int r[PA_E], c[PA_E], bk[PA_E];
  float v[PA_E];
  #pragma unroll
  for (int j = 0; j < PA_E; ++j) {
    int e = base + t + j * PA_T;
    if (e < E) {
      r[j] = erow[e]; c[j] = ecol[e]; v[j] = eval[e];
      bk[j] = r[j] / RPB;
      atomicAdd(&h[bk[j]], 1);
    } else r[j] = -1;
  }
  __syncthreads();
  // chunked exclusive scan of h -> lstart; reserve global chunks per bucket
  {
    int lo = t * C;
    int hv[C];
    int s = 0;
    #pragma unroll
    for (int i = 0; i < C; ++i) { hv[i] = h[lo + i]; s += hv[i]; }
    csum[t] = s;
    __syncthreads();
    for (int off = 1; off < PA_T; off <<= 1) {
      int x = (t >= off) ? csum[t - off] : 0;
      __syncthreads();
      csum[t] += x;
      __syncthreads();
    }
    int run = csum[t] - s;
    #pragma unroll
    for (int i = 0; i < C; ++i) {
      lstart[lo + i] = run; run += hv[i];
      if (hv[i] > 0) cbase[lo + i] = bbase[lo + i] + atomicAdd(&bfill[lo + i], hv[i]);
    }
  }
  __syncthreads();
  #pragma unroll
  for (int j = 0; j < PA_E; ++j) {
    if (r[j] >= 0) {
      int rank = atomicAdd(&lfill[bk[j]], 1);
      int lpos = lstart[bk[j]] + rank;
      stage[lpos] = make_int4(r[j], c[j], __float_as_int(v[j]), 0);
      sdest[lpos] = cbase[bk[j]] + rank;
    }
  }
  __syncthreads();
  int tot = E - base; if (tot > PA_EDGES) tot = PA_EDGES;
  for (int p = t; p < tot; p += PA_T) binned[sdest[p]] = stage[p];
}

// pass B: one block per bucket; in-LDS sub-CSR build + coalesced cpack/rowptr writes
__global__ void k_binB(const int4* __restrict__ binned, const int* __restrict__ bbase,
                       int* __restrict__ rowptr, float2* __restrict__ cpack,
                       int N, int E, int RPB) {
  __shared__ int lh[RPB_MAX];
  __shared__ int lrp[RPB_MAX + 1];
  __shared__ int lf[RPB_MAX];
  __shared__ int csum[PB_T];
  __shared__ float2 st[PB_CAP];
  int b = blockIdx.x;
  int t = threadIdx.x;
  int row_lo = b * RPB;
  int row_hi = row_lo + RPB; if (row_hi > N) row_hi = N;
  int nrows = row_hi - row_lo;
  if (b == NB - 1 && t == 0) rowptr[N] = E;
  if (nrows <= 0) return;
  int seg_lo = bbase[b];
  int cnt = bbase[b + 1] - seg_lo;
  for (int i = t; i < nrows; i += PB_T) { lh[i] = 0; lf[i] = 0; }
  __syncthreads();
  // phase 1: row histogram
  for (int p = t; p < cnt; p += PB_T)
    atomicAdd(&lh[binned[seg_lo + p].x - row_lo], 1);
  __syncthreads();
  // exclusive scan lh[0..nrows) -> lrp
  {
    int chunk = (nrows + PB_T - 1) / PB_T;
    int lo = t * chunk; if (lo > nrows) lo = nrows;
    int hi = lo + chunk; if (hi > nrows) hi = nrows;
    int s = 0;
    for (int i = lo; i < hi; ++i) s += lh[i];
    csum[t] = s;
    __syncthreads();
    for (int off = 1; off < PB_T; off <<= 1) {
      int x = (t >= off) ? csum[t - off] : 0;
      __syncthreads();
      csum[t] += x;
      __syncthreads();
    }
    int run = csum[t] - s;
    for (int i = lo; i < hi; ++i) { lrp[i] = run; run += lh[i]; }
    if (t == PB_T - 1) lrp[nrows] = run;  // == cnt
  }
  __syncthreads();
  // write rowptr slice (coalesced)
  for (int i = t; i < nrows; i += PB_T) rowptr[row_lo + i] = seg_lo + lrp[i];
  // phase 2: slot assignment via LDS atomics, stage payload
  bool fits = (cnt <= PB_CAP);
  for (int p = t; p < cnt; p += PB_T) {
    int4 q = binned[seg_lo + p];
    int lr = q.x - row_lo;
    int slot = lrp[lr] + atomicAdd(&lf[lr], 1);
    float2 pay = make_float2(__int_as_float(q.y), __int_as_float(q.z));
    if (fits) st[slot] = pay;
    else cpack[seg_lo + slot] = pay;   // fallback, not expected
  }
  __syncthreads();
  if (fits)
    for (int p = t; p < cnt; p += PB_T) cpack[seg_lo + p] = st[p];
}

// convert f32 tables -> packed bf16 emb0 (halves the random-gather footprint)
__global__ void k_cvt(const float4* __restrict__ ut4, const float4* __restrict__ it4,
                      uint2* __restrict__ embh, int nu16, int tot16) {
  int i = blockIdx.x * blockDim.x + threadIdx.x;
  if (i >= tot16) return;
  float4 f = (i < nu16) ? ut4[i] : it4[i - nu16];
  embh[i] = make_uint2(bfpack(f.x, f.y), bfpack(f.z, f.w));
}

// one wave per row; lanes = 8 edge-slots x 8 uint4-lanes (16B/lane); f32 accum
__global__ void k_prop(const uint4* __restrict__ ein, uint4* __restrict__ eout,
                       const int* __restrict__ rowptr, const float2* __restrict__ cpack,
                       int N) {
  int w = (blockIdx.x * blockDim.x + threadIdx.x) >> 6;
  int lane = threadIdx.x & 63;
  if (w >= N) return;
  int sub = lane >> 3;      // edge slot 0..7
  int d8  = lane & 7;       // uint4 index (8 bf16 dims per lane)
  int beg = rowptr[w], end = rowptr[w + 1];
  float a0 = 0.f, a1 = 0.f, a2 = 0.f, a3 = 0.f;
  float a4 = 0.f, a5 = 0.f, a6 = 0.f, a7 = 0.f;
  for (int k = beg + sub; k < end; k += 8) {
    float2 p = cpack[k];
    int   c = __float_as_int(p.x);
    float vv = p.y;
    uint4 q = ein[(size_t)c * 8 + d8];
    a0 = fmaf(vv, bflo(q.x), a0); a1 = fmaf(vv, bfhi(q.x), a1);
    a2 = fmaf(vv, bflo(q.y), a2); a3 = fmaf(vv, bfhi(q.y), a3);
    a4 = fmaf(vv, bflo(q.z), a4); a5 = fmaf(vv, bfhi(q.z), a5);
    a6 = fmaf(vv, bflo(q.w), a6); a7 = fmaf(vv, bfhi(q.w), a7);
  }
  #pragma unroll
  for (int off = 8; off < 64; off <<= 1) {
    a0 += __shfl_xor(a0, off); a1 += __shfl_xor(a1, off);
    a2 += __shfl_xor(a2, off); a3 += __shfl_xor(a3, off);
    a4 += __shfl_xor(a4, off); a5 += __shfl_xor(a5, off);
    a6 += __shfl_xor(a6, off); a7 += __shfl_xor(a7, off);
  }
  if (sub == 0)
    eout[(size_t)w * 8 + d8] = make_uint4(bfpack(a0, a1), bfpack(a2, a3),
                                          bfpack(a4, a5), bfpack(a6, a7));
}

// fused: hop-0 (f32 exact) + hop-1/2 (bf16) + on-the-fly hop-3 + sigmoid/softmax dot
__global__ void k_final(const float* __restrict__ ut, const float* __restrict__ it,
                        const unsigned short* __restrict__ emb1,
                        const unsigned short* __restrict__ emb2,
                        const int* __restrict__ rowptr, const float2* __restrict__ cpack,
                        const int* __restrict__ users, const int* __restrict__ items,
                        const float* __restrict__ xij, const float* __restrict__ xtab,
                        float* __restrict__ out, int B, int NU) {
  int w = (blockIdx.x * blockDim.x + threadIdx.x) >> 6;
  int lane = threadIdx.x & 63;
  if (w >= B) return;
  int u = users[w];
  int v = NU + items[w];

  float accu = ut[(size_t)u * D + lane] + bf2f(emb1[(size_t)u * D + lane])
             + bf2f(emb2[(size_t)u * D + lane]);
  {
    int beg = rowptr[u], end = rowptr[u + 1];
    for (int k = beg; k < end; ++k) {
      float2 p = cpack[k];
      int c = __float_as_int(p.x);
      accu = fmaf(p.y, bf2f(emb2[(size_t)c * D + lane]), accu);
    }
  }
  float accv = it[(size_t)(v - NU) * D + lane] + bf2f(emb1[(size_t)v * D + lane])
             + bf2f(emb2[(size_t)v * D + lane]);
  {
    int beg = rowptr[v], end = rowptr[v + 1];
    for (int k = beg; k < end; ++k) {
      float2 p = cpack[k];
      int c = __float_as_int(p.x);
      accv = fmaf(p.y, bf2f(emb2[(size_t)c * D + lane]), accv);
    }
  }

  float ue = accu * 0.25f;   // /(L+1)
  float ie = accv * 0.25f;
  float xs = xij[w] - 0.3f;
  float xe = (lane < 8) ? xtab[lane] * xs : 0.f;

  float m = (lane < 8) ? fmaxf(ie, xe) : ie;
  for (int off = 32; off; off >>= 1) m = fmaxf(m, __shfl_xor(m, off));
  float e1 = expf(ie - m);
  float e2 = (lane < 8) ? expf(xe - m) : 0.f;
  float s = e1 + e2;
  for (int off = 32; off; off >>= 1) s += __shfl_xor(s, off);
  float inv = 1.f / s;

  float sig1 = 1.f / (1.f + expf(-ue));
  float term = sig1 * e1 * inv;
  if (lane < 8) {
    float sig2 = 1.f / (1.f + expf(-xe));
    term += sig2 * e2 * inv;
  }
  for (int off = 32; off; off >>= 1) term += __shfl_xor(term, off);
  if (lane == 0) out[w] = term;
}

extern "C" void kernel_launch(void* const* d_in, const int* in_sizes, int n_in,
                              void* d_out, int out_size, void* d_ws, size_t ws_size,
                              hipStream_t stream) {
  const int*   users = (const int*)d_in[0];
  const int*   items = (const int*)d_in[1];
  const float* xij   = (const float*)d_in[2];
  const float* utab  = (const float*)d_in[3];
  const float* itab  = (const float*)d_in[4];
  const float* xtab  = (const float*)d_in[5];
  const int*   erow  = (const int*)d_in[6];
  const int*   ecol  = (const int*)d_in[7];
  const float* evalp = (const float*)d_in[8];
  float* out = (float*)d_out;

  int B  = in_sizes[0];
  int NU = in_sizes[3] / D;
  int NI = in_sizes[4] / D;
  int N  = NU + NI;
  int E  = in_sizes[6];
  int RPB = (N + NB - 1) / NB;   // rows per bucket (147 for N=150000)

  char* ws = (char*)d_ws;
  size_t off = 0;
  auto carve = [&](size_t bytes) {
    void* p = ws + off;
    off += (bytes + 255) & ~(size_t)255;
    return p;
  };
  uint2*  embh0  = (uint2*)carve((size_t)N * D * 2);   // bf16 packed
  uint2*  embh1  = (uint2*)carve((size_t)N * D * 2);
  uint2*  embh2  = (uint2*)carve((size_t)N * D * 2);
  int*    rowptr = (int*)carve((size_t)(N + 1) * 4);
  int*    bhist  = (int*)carve((size_t)NB * 4);
  int*    bfill  = (int*)carve((size_t)NB * 4);
  int*    bbase  = (int*)carve((size_t)(NB + 1) * 4);
  int4*   binned = (int4*)carve((size_t)E * 16);
  float2* cpack  = (float2*)carve((size_t)E * 8);
  (void)ws_size; (void)n_in; (void)out_size;

  int ablocks = (E + PA_EDGES - 1) / PA_EDGES;

  // --- CSR build via two-pass binned counting sort ---
  hipLaunchKernelGGL(k_zero, dim3((2 * NB + 255) / 256), dim3(256), 0, stream,
                     bhist, 2 * NB);   // bhist + bfill (adjacent carves)
  hipLaunchKernelGGL(k_bhist, dim3(ablocks), dim3(PA_T), 0, stream, erow, bhist, E, RPB);
  hipLaunchKernelGGL(k_bscan, dim3(1), dim3(PA_T), 0, stream, bhist, bbase, E);
  hipLaunchKernelGGL(k_binA, dim3(ablocks), dim3(PA_T), 0, stream,
                     erow, ecol, evalp, bbase, bfill, binned, E, RPB);
  hipLaunchKernelGGL(k_binB, dim3(NB), dim3(PB_T), 0, stream,
                     binned, bbase, rowptr, cpack, N, E, RPB);

  // --- tables -> bf16 emb0 ---
  int tot16 = N * 16, nu16 = NU * 16;
  hipLaunchKernelGGL(k_cvt, dim3((tot16 + 255) / 256), dim3(256), 0, stream,
                     (const float4*)utab, (const float4*)itab, embh0, nu16, tot16);

  // --- hops 1,2 full (bf16); hop 3 fused into final ---
  hipLaunchKernelGGL(k_prop, dim3((N * 64 + 255) / 256), dim3(256), 0, stream,
                     (const uint4*)embh0, (uint4*)embh1, rowptr, cpack, N);
  hipLaunchKernelGGL(k_prop, dim3((N * 64 + 255) / 256), dim3(256), 0, stream,
                     (const uint4*)embh1, (uint4*)embh2, rowptr, cpack, N);

  hipLaunchKernelGGL(k_final, dim3((B * 64 + 255) / 256), dim3(256), 0, stream,
                     utab, itab, (const unsigned short*)embh1,
                     (const unsigned short*)embh2, rowptr, cpack,
                     users, items, xij, xtab, out, B, NU);
}

// Round 16
// 261.110 us; speedup vs baseline: 1.1577x; 1.1577x over previous
//
#include <hip/hip_runtime.h>
#include <math.h>

#define D 64
#define NB 256            // row buckets
#define PA_T 256
#define PA_E 8
#define PA_EDGES (PA_T * PA_E)   // 2048 edges per binA block
#define PB_T 1024         // binB threads (parallelism via threads, not blocks)
#define PB_CAP 6400       // staged edges per bucket (mean ~4882, sigma ~70)
#define RPB_MAX 640       // max rows per bucket (actual 587 for N=150000)

// ---- bf16 pack/unpack (RNE) ----
__device__ __forceinline__ unsigned bfpack(float a, float b) {
  unsigned ua = __float_as_uint(a);
  unsigned ub = __float_as_uint(b);
  ua = (ua + 0x7FFFu + ((ua >> 16) & 1u)) >> 16;
  ub = (ub + 0x7FFFu + ((ub >> 16) & 1u)) >> 16;
  return (ua & 0xFFFFu) | (ub << 16);
}
__device__ __forceinline__ float bflo(unsigned u) { return __uint_as_float(u << 16); }
__device__ __forceinline__ float bfhi(unsigned u) { return __uint_as_float(u & 0xFFFF0000u); }
__device__ __forceinline__ float bf2f(unsigned short s) {
  return __uint_as_float(((unsigned)s) << 16);
}

__global__ void k_zero(int* __restrict__ a, int n) {
  int i = blockIdx.x * blockDim.x + threadIdx.x;
  if (i < n) a[i] = 0;
}

// per-block LDS bucket histogram -> few global atomics
__global__ void k_bhist(const int* __restrict__ erow, int* __restrict__ bhist,
                        int E, int RPB) {
  __shared__ int h[NB];
  int t = threadIdx.x;
  h[t] = 0;
  __syncthreads();
  int base = blockIdx.x * PA_EDGES;
  #pragma unroll
  for (int j = 0; j < PA_E; ++j) {
    int e = base + t + j * PA_T;
    if (e < E) atomicAdd(&h[erow[e] / RPB], 1);
  }
  __syncthreads();
  if (h[t] > 0) atomicAdd(&bhist[t], h[t]);
}

// exclusive scan of NB bucket counts -> bbase[NB+1]
__global__ void k_bscan(const int* __restrict__ bhist, int* __restrict__ bbase, int E) {
  __shared__ int sh[NB];
  int t = threadIdx.x;
  int v = bhist[t];
  sh[t] = v;
  __syncthreads();
  for (int off = 1; off < NB; off <<= 1) {
    int x = (t >= off) ? sh[t - off] : 0;
    __syncthreads();
    sh[t] += x;
    __syncthreads();
  }
  bbase[t] = sh[t] - v;
  if (t == NB - 1) bbase[NB] = E;
}

// pass A: block-local counting sort by bucket; packed int2 records; coalesced writes
__global__ void k_binA(const int* __restrict__ erow, const int* __restrict__ ecol,
                       const float* __restrict__ eval, const int* __restrict__ bbase,
                       int* __restrict__ bfill, int2* __restrict__ binned,
                       int E, int RPB) {
  __shared__ int h[NB];
  __shared__ int lstart[NB];
  __shared__ int cbase[NB];
  __shared__ int lfill[NB];
  __shared__ int2 stage[PA_EDGES];
  __shared__ int sdest[PA_EDGES];
  int t = threadIdx.x;
  int base = blockIdx.x * PA_EDGES;
  h[t] = 0; lfill[t] = 0;
  __syncthreads();
  int r[PA_E], c[PA_E], bk[PA_E];
  float v[PA_E];
  #pragma unroll
  for (int j = 0; j < PA_E; ++j) {
    int e = base + t + j * PA_T;
    if (e < E) {
      r[j] = erow[e]; c[j] = ecol[e]; v[j] = eval[e];
      bk[j] = r[j] / RPB;
      atomicAdd(&h[bk[j]], 1);
    } else r[j] = -1;
  }
  __syncthreads();
  int myh = h[t];
  lstart[t] = myh;
  __syncthreads();
  for (int off = 1; off < NB; off <<= 1) {
    int x = (t >= off) ? lstart[t - off] : 0;
    __syncthreads();
    lstart[t] += x;
    __syncthreads();
  }
  int excl = lstart[t] - myh;
  __syncthreads();
  lstart[t] = excl;
  if (myh > 0) cbase[t] = bbase[t] + atomicAdd(&bfill[t], myh);
  __syncthreads();
  #pragma unroll
  for (int j = 0; j < PA_E; ++j) {
    if (r[j] >= 0) {
      int rank = atomicAdd(&lfill[bk[j]], 1);
      int lpos = lstart[bk[j]] + rank;
      int lr = r[j] - bk[j] * RPB;            // bucket-local row, 10 bits
      stage[lpos] = make_int2((lr << 18) | c[j], __float_as_int(v[j]));
      sdest[lpos] = cbase[bk[j]] + rank;
    }
  }
  __syncthreads();
  int tot = E - base; if (tot > PA_EDGES) tot = PA_EDGES;
  for (int p = t; p < tot; p += PA_T) binned[sdest[p]] = stage[p];
}

// pass B: one 1024-thread block per bucket; in-LDS sub-CSR + coalesced writes
__global__ void k_binB(const int2* __restrict__ binned, const int* __restrict__ bbase,
                       int* __restrict__ rowptr, float2* __restrict__ cpack,
                       int N, int E, int RPB) {
  __shared__ int lh[RPB_MAX];
  __shared__ int lrp[RPB_MAX + 1];
  __shared__ int lf[RPB_MAX];
  __shared__ int csum[PB_T];
  __shared__ float2 st[PB_CAP];
  int b = blockIdx.x;
  int t = threadIdx.x;
  int row_lo = b * RPB;
  int row_hi = row_lo + RPB; if (row_hi > N) row_hi = N;
  int nrows = row_hi - row_lo;
  if (b == NB - 1 && t == 0) rowptr[N] = E;
  if (nrows <= 0) return;
  int seg_lo = bbase[b];
  int cnt = bbase[b + 1] - seg_lo;
  for (int i = t; i < nrows; i += PB_T) { lh[i] = 0; lf[i] = 0; }
  __syncthreads();
  // phase 1: row histogram
  for (int p = t; p < cnt; p += PB_T)
    atomicAdd(&lh[((unsigned)binned[seg_lo + p].x) >> 18], 1);
  __syncthreads();
  // exclusive scan lh[0..nrows) -> lrp (nrows <= 640 < PB_T: one row per thread)
  {
    int s = (t < nrows) ? lh[t] : 0;
    csum[t] = s;
    __syncthreads();
    for (int off = 1; off < PB_T; off <<= 1) {
      int x = (t >= off) ? csum[t - off] : 0;
      __syncthreads();
      csum[t] += x;
      __syncthreads();
    }
    if (t < nrows) lrp[t] = csum[t] - s;
    if (t == nrows - 1) lrp[nrows] = csum[t];   // == cnt
  }
  __syncthreads();
  // write rowptr slice (coalesced)
  for (int i = t; i < nrows; i += PB_T) rowptr[row_lo + i] = seg_lo + lrp[i];
  // phase 2: slot assignment via LDS atomics, stage payload
  bool fits = (cnt <= PB_CAP);
  for (int p = t; p < cnt; p += PB_T) {
    int2 q = binned[seg_lo + p];
    int lr = ((unsigned)q.x) >> 18;
    int cc = q.x & 0x3FFFF;
    int slot = lrp[lr] + atomicAdd(&lf[lr], 1);
    float2 pay = make_float2(__int_as_float(cc), __int_as_float(q.y));
    if (fits) st[slot] = pay;
    else cpack[seg_lo + slot] = pay;   // fallback, not expected
  }
  __syncthreads();
  if (fits)
    for (int p = t; p < cnt; p += PB_T) cpack[seg_lo + p] = st[p];
}

// convert f32 tables -> packed bf16 emb0 (halves the random-gather footprint)
__global__ void k_cvt(const float4* __restrict__ ut4, const float4* __restrict__ it4,
                      uint2* __restrict__ embh, int nu16, int tot16) {
  int i = blockIdx.x * blockDim.x + threadIdx.x;
  if (i >= tot16) return;
  float4 f = (i < nu16) ? ut4[i] : it4[i - nu16];
  embh[i] = make_uint2(bfpack(f.x, f.y), bfpack(f.z, f.w));
}

// one wave per row; lanes = 8 edge-slots x 8 uint4-lanes (16B/lane); f32 accum
__global__ void k_prop(const uint4* __restrict__ ein, uint4* __restrict__ eout,
                       const int* __restrict__ rowptr, const float2* __restrict__ cpack,
                       int N) {
  int w = (blockIdx.x * blockDim.x + threadIdx.x) >> 6;
  int lane = threadIdx.x & 63;
  if (w >= N) return;
  int sub = lane >> 3;      // edge slot 0..7
  int d8  = lane & 7;       // uint4 index (8 bf16 dims per lane)
  int beg = rowptr[w], end = rowptr[w + 1];
  float a0 = 0.f, a1 = 0.f, a2 = 0.f, a3 = 0.f;
  float a4 = 0.f, a5 = 0.f, a6 = 0.f, a7 = 0.f;
  for (int k = beg + sub; k < end; k += 8) {
    float2 p = cpack[k];
    int   c = __float_as_int(p.x);
    float vv = p.y;
    uint4 q = ein[(size_t)c * 8 + d8];
    a0 = fmaf(vv, bflo(q.x), a0); a1 = fmaf(vv, bfhi(q.x), a1);
    a2 = fmaf(vv, bflo(q.y), a2); a3 = fmaf(vv, bfhi(q.y), a3);
    a4 = fmaf(vv, bflo(q.z), a4); a5 = fmaf(vv, bfhi(q.z), a5);
    a6 = fmaf(vv, bflo(q.w), a6); a7 = fmaf(vv, bfhi(q.w), a7);
  }
  #pragma unroll
  for (int off = 8; off < 64; off <<= 1) {
    a0 += __shfl_xor(a0, off); a1 += __shfl_xor(a1, off);
    a2 += __shfl_xor(a2, off); a3 += __shfl_xor(a3, off);
    a4 += __shfl_xor(a4, off); a5 += __shfl_xor(a5, off);
    a6 += __shfl_xor(a6, off); a7 += __shfl_xor(a7, off);
  }
  if (sub == 0)
    eout[(size_t)w * 8 + d8] = make_uint4(bfpack(a0, a1), bfpack(a2, a3),
                                          bfpack(a4, a5), bfpack(a6, a7));
}

// fused: hop-0 (f32 exact) + hop-1/2 (bf16) + on-the-fly hop-3 + sigmoid/softmax dot
__global__ void k_final(const float* __restrict__ ut, const float* __restrict__ it,
                        const unsigned short* __restrict__ emb1,
                        const unsigned short* __restrict__ emb2,
                        const int* __restrict__ rowptr, const float2* __restrict__ cpack,
                        const int* __restrict__ users, const int* __restrict__ items,
                        const float* __restrict__ xij, const float* __restrict__ xtab,
                        float* __restrict__ out, int B, int NU) {
  int w = (blockIdx.x * blockDim.x + threadIdx.x) >> 6;
  int lane = threadIdx.x & 63;
  if (w >= B) return;
  int u = users[w];
  int v = NU + items[w];

  float accu = ut[(size_t)u * D + lane] + bf2f(emb1[(size_t)u * D + lane])
             + bf2f(emb2[(size_t)u * D + lane]);
  {
    int beg = rowptr[u], end = rowptr[u + 1];
    for (int k = beg; k < end; ++k) {
      float2 p = cpack[k];
      int c = __float_as_int(p.x);
      accu = fmaf(p.y, bf2f(emb2[(size_t)c * D + lane]), accu);
    }
  }
  float accv = it[(size_t)(v - NU) * D + lane] + bf2f(emb1[(size_t)v * D + lane])
             + bf2f(emb2[(size_t)v * D + lane]);
  {
    int beg = rowptr[v], end = rowptr[v + 1];
    for (int k = beg; k < end; ++k) {
      float2 p = cpack[k];
      int c = __float_as_int(p.x);
      accv = fmaf(p.y, bf2f(emb2[(size_t)c * D + lane]), accv);
    }
  }

  float ue = accu * 0.25f;   // /(L+1)
  float ie = accv * 0.25f;
  float xs = xij[w] - 0.3f;
  float xe = (lane < 8) ? xtab[lane] * xs : 0.f;

  float m = (lane < 8) ? fmaxf(ie, xe) : ie;
  for (int off = 32; off; off >>= 1) m = fmaxf(m, __shfl_xor(m, off));
  float e1 = expf(ie - m);
  float e2 = (lane < 8) ? expf(xe - m) : 0.f;
  float s = e1 + e2;
  for (int off = 32; off; off >>= 1) s += __shfl_xor(s, off);
  float inv = 1.f / s;

  float sig1 = 1.f / (1.f + expf(-ue));
  float term = sig1 * e1 * inv;
  if (lane < 8) {
    float sig2 = 1.f / (1.f + expf(-xe));
    term += sig2 * e2 * inv;
  }
  for (int off = 32; off; off >>= 1) term += __shfl_xor(term, off);
  if (lane == 0) out[w] = term;
}

extern "C" void kernel_launch(void* const* d_in, const int* in_sizes, int n_in,
                              void* d_out, int out_size, void* d_ws, size_t ws_size,
                              hipStream_t stream) {
  const int*   users = (const int*)d_in[0];
  const int*   items = (const int*)d_in[1];
  const float* xij   = (const float*)d_in[2];
  const float* utab  = (const float*)d_in[3];
  const float* itab  = (const float*)d_in[4];
  const float* xtab  = (const float*)d_in[5];
  const int*   erow  = (const int*)d_in[6];
  const int*   ecol  = (const int*)d_in[7];
  const float* evalp = (const float*)d_in[8];
  float* out = (float*)d_out;

  int B  = in_sizes[0];
  int NU = in_sizes[3] / D;
  int NI = in_sizes[4] / D;
  int N  = NU + NI;
  int E  = in_sizes[6];
  int RPB = (N + NB - 1) / NB;   // rows per bucket (587 for N=150000)

  char* ws = (char*)d_ws;
  size_t off = 0;
  auto carve = [&](size_t bytes) {
    void* p = ws + off;
    off += (bytes + 255) & ~(size_t)255;
    return p;
  };
  uint2*  embh0  = (uint2*)carve((size_t)N * D * 2);   // bf16 packed
  uint2*  embh1  = (uint2*)carve((size_t)N * D * 2);
  uint2*  embh2  = (uint2*)carve((size_t)N * D * 2);
  int*    rowptr = (int*)carve((size_t)(N + 1) * 4);
  int*    bhist  = (int*)carve((size_t)NB * 4);
  int*    bfill  = (int*)carve((size_t)NB * 4);
  int*    bbase  = (int*)carve((size_t)(NB + 1) * 4);
  int2*   binned = (int2*)carve((size_t)E * 8);
  float2* cpack  = (float2*)carve((size_t)E * 8);
  (void)ws_size; (void)n_in; (void)out_size;

  int ablocks = (E + PA_EDGES - 1) / PA_EDGES;

  // --- CSR build via two-pass binned counting sort ---
  hipLaunchKernelGGL(k_zero, dim3((2 * NB + 255) / 256), dim3(256), 0, stream,
                     bhist, 2 * NB);   // bhist + bfill (adjacent carves)
  hipLaunchKernelGGL(k_bhist, dim3(ablocks), dim3(PA_T), 0, stream, erow, bhist, E, RPB);
  hipLaunchKernelGGL(k_bscan, dim3(1), dim3(NB), 0, stream, bhist, bbase, E);
  hipLaunchKernelGGL(k_binA, dim3(ablocks), dim3(PA_T), 0, stream,
                     erow, ecol, evalp, bbase, bfill, binned, E, RPB);
  hipLaunchKernelGGL(k_binB, dim3(NB), dim3(PB_T), 0, stream,
                     binned, bbase, rowptr, cpack, N, E, RPB);

  // --- tables -> bf16 emb0 ---
  int tot16 = N * 16, nu16 = NU * 16;
  hipLaunchKernelGGL(k_cvt, dim3((tot16 + 255) / 256), dim3(256), 0, stream,
                     (const float4*)utab, (const float4*)itab, embh0, nu16, tot16);

  // --- hops 1,2 full (bf16); hop 3 fused into final ---
  hipLaunchKernelGGL(k_prop, dim3((N * 64 + 255) / 256), dim3(256), 0, stream,
                     (const uint4*)embh0, (uint4*)embh1, rowptr, cpack, N);
  hipLaunchKernelGGL(k_prop, dim3((N * 64 + 255) / 256), dim3(256), 0, stream,
                     (const uint4*)embh1, (uint4*)embh2, rowptr, cpack, N);

  hipLaunchKernelGGL(k_final, dim3((B * 64 + 255) / 256), dim3(256), 0, stream,
                     utab, itab, (const unsigned short*)embh1,
                     (const unsigned short*)embh2, rowptr, cpack,
                     users, items, xij, xtab, out, B, NU);
}

// Round 17
// 238.384 us; speedup vs baseline: 1.2680x; 1.0953x over previous
//
#include <hip/hip_runtime.h>
#include <math.h>

#define D 64
#define NB 256            // row buckets
#define PA_T 256
#define PA_E 8
#define PA_EDGES (PA_T * PA_E)   // 2048 edges per binA block
#define PB_T 1024         // binB threads (parallelism via threads, not blocks)
#define PB_CAP 6400       // staged edges per bucket (mean ~4882, sigma ~70)
#define RPB_MAX 640       // max rows per bucket (actual 587 for N=150000)

// ---- bf16 pack/unpack (RNE) ----
__device__ __forceinline__ unsigned bfpack(float a, float b) {
  unsigned ua = __float_as_uint(a);
  unsigned ub = __float_as_uint(b);
  ua = (ua + 0x7FFFu + ((ua >> 16) & 1u)) >> 16;
  ub = (ub + 0x7FFFu + ((ub >> 16) & 1u)) >> 16;
  return (ua & 0xFFFFu) | (ub << 16);
}
__device__ __forceinline__ float bflo(unsigned u) { return __uint_as_float(u << 16); }
__device__ __forceinline__ float bfhi(unsigned u) { return __uint_as_float(u & 0xFFFF0000u); }
__device__ __forceinline__ float bf2f(unsigned short s) {
  return __uint_as_float(((unsigned)s) << 16);
}

__global__ void k_zero(int* __restrict__ a, int n) {
  int i = blockIdx.x * blockDim.x + threadIdx.x;
  if (i < n) a[i] = 0;
}

// per-block LDS bucket histogram -> few global atomics
__global__ void k_bhist(const int* __restrict__ erow, int* __restrict__ bhist,
                        int E, int RPB) {
  __shared__ int h[NB];
  int t = threadIdx.x;
  h[t] = 0;
  __syncthreads();
  int base = blockIdx.x * PA_EDGES;
  #pragma unroll
  for (int j = 0; j < PA_E; ++j) {
    int e = base + t + j * PA_T;
    if (e < E) atomicAdd(&h[erow[e] / RPB], 1);
  }
  __syncthreads();
  if (h[t] > 0) atomicAdd(&bhist[t], h[t]);
}

// exclusive scan of NB bucket counts -> bbase[NB+1]
__global__ void k_bscan(const int* __restrict__ bhist, int* __restrict__ bbase, int E) {
  __shared__ int sh[NB];
  int t = threadIdx.x;
  int v = bhist[t];
  sh[t] = v;
  __syncthreads();
  for (int off = 1; off < NB; off <<= 1) {
    int x = (t >= off) ? sh[t - off] : 0;
    __syncthreads();
    sh[t] += x;
    __syncthreads();
  }
  bbase[t] = sh[t] - v;
  if (t == NB - 1) bbase[NB] = E;
}

// pass A: block-local counting sort by bucket; packed int2 records; coalesced writes
__global__ void k_binA(const int* __restrict__ erow, const int* __restrict__ ecol,
                       const float* __restrict__ eval, const int* __restrict__ bbase,
                       int* __restrict__ bfill, int2* __restrict__ binned,
                       int E, int RPB) {
  __shared__ int h[NB];
  __shared__ int lstart[NB];
  __shared__ int cbase[NB];
  __shared__ int lfill[NB];
  __shared__ int2 stage[PA_EDGES];
  __shared__ int sdest[PA_EDGES];
  int t = threadIdx.x;
  int base = blockIdx.x * PA_EDGES;
  h[t] = 0; lfill[t] = 0;
  __syncthreads();
  int r[PA_E], c[PA_E], bk[PA_E];
  float v[PA_E];
  #pragma unroll
  for (int j = 0; j < PA_E; ++j) {
    int e = base + t + j * PA_T;
    if (e < E) {
      r[j] = erow[e]; c[j] = ecol[e]; v[j] = eval[e];
      bk[j] = r[j] / RPB;
      atomicAdd(&h[bk[j]], 1);
    } else r[j] = -1;
  }
  __syncthreads();
  int myh = h[t];
  lstart[t] = myh;
  __syncthreads();
  for (int off = 1; off < NB; off <<= 1) {
    int x = (t >= off) ? lstart[t - off] : 0;
    __syncthreads();
    lstart[t] += x;
    __syncthreads();
  }
  int excl = lstart[t] - myh;
  __syncthreads();
  lstart[t] = excl;
  if (myh > 0) cbase[t] = bbase[t] + atomicAdd(&bfill[t], myh);
  __syncthreads();
  #pragma unroll
  for (int j = 0; j < PA_E; ++j) {
    if (r[j] >= 0) {
      int rank = atomicAdd(&lfill[bk[j]], 1);
      int lpos = lstart[bk[j]] + rank;
      int lr = r[j] - bk[j] * RPB;            // bucket-local row, 10 bits
      stage[lpos] = make_int2((lr << 18) | c[j], __float_as_int(v[j]));
      sdest[lpos] = cbase[bk[j]] + rank;
    }
  }
  __syncthreads();
  int tot = E - base; if (tot > PA_EDGES) tot = PA_EDGES;
  for (int p = t; p < tot; p += PA_T) binned[sdest[p]] = stage[p];
}

// pass B: one 1024-thread block per bucket; in-LDS sub-CSR + coalesced writes
__global__ void k_binB(const int2* __restrict__ binned, const int* __restrict__ bbase,
                       int* __restrict__ rowptr, float2* __restrict__ cpack,
                       int N, int E, int RPB) {
  __shared__ int lh[RPB_MAX];
  __shared__ int lrp[RPB_MAX + 1];
  __shared__ int lf[RPB_MAX];
  __shared__ int csum[PB_T];
  __shared__ float2 st[PB_CAP];
  int b = blockIdx.x;
  int t = threadIdx.x;
  int row_lo = b * RPB;
  int row_hi = row_lo + RPB; if (row_hi > N) row_hi = N;
  int nrows = row_hi - row_lo;
  if (b == NB - 1 && t == 0) rowptr[N] = E;
  if (nrows <= 0) return;
  int seg_lo = bbase[b];
  int cnt = bbase[b + 1] - seg_lo;
  for (int i = t; i < nrows; i += PB_T) { lh[i] = 0; lf[i] = 0; }
  __syncthreads();
  // phase 1: row histogram
  for (int p = t; p < cnt; p += PB_T)
    atomicAdd(&lh[((unsigned)binned[seg_lo + p].x) >> 18], 1);
  __syncthreads();
  // exclusive scan lh[0..nrows) -> lrp (nrows <= 640 < PB_T: one row per thread)
  {
    int s = (t < nrows) ? lh[t] : 0;
    csum[t] = s;
    __syncthreads();
    for (int off = 1; off < PB_T; off <<= 1) {
      int x = (t >= off) ? csum[t - off] : 0;
      __syncthreads();
      csum[t] += x;
      __syncthreads();
    }
    if (t < nrows) lrp[t] = csum[t] - s;
    if (t == nrows - 1) lrp[nrows] = csum[t];   // == cnt
  }
  __syncthreads();
  // write rowptr slice (coalesced)
  for (int i = t; i < nrows; i += PB_T) rowptr[row_lo + i] = seg_lo + lrp[i];
  // phase 2: slot assignment via LDS atomics, stage payload
  bool fits = (cnt <= PB_CAP);
  for (int p = t; p < cnt; p += PB_T) {
    int2 q = binned[seg_lo + p];
    int lr = ((unsigned)q.x) >> 18;
    int cc = q.x & 0x3FFFF;
    int slot = lrp[lr] + atomicAdd(&lf[lr], 1);
    float2 pay = make_float2(__int_as_float(cc), __int_as_float(q.y));
    if (fits) st[slot] = pay;
    else cpack[seg_lo + slot] = pay;   // fallback, not expected
  }
  __syncthreads();
  if (fits)
    for (int p = t; p < cnt; p += PB_T) cpack[seg_lo + p] = st[p];
}

// convert f32 tables -> packed bf16 emb0 (halves the random-gather footprint)
__global__ void k_cvt(const float4* __restrict__ ut4, const float4* __restrict__ it4,
                      uint2* __restrict__ embh, int nu16, int tot16) {
  int i = blockIdx.x * blockDim.x + threadIdx.x;
  if (i >= tot16) return;
  float4 f = (i < nu16) ? ut4[i] : it4[i - nu16];
  embh[i] = make_uint2(bfpack(f.x, f.y), bfpack(f.z, f.w));
}

// one row per 8-lane group (8 rows/wave); serial edge loop, NO cross-lane reduce.
// per edge: broadcast 8B cpack load + one 16B row-gather + 8 fma per lane.
__global__ void k_prop(const uint4* __restrict__ ein, uint4* __restrict__ eout,
                       const int* __restrict__ rowptr, const float2* __restrict__ cpack,
                       int N) {
  int gid = blockIdx.x * blockDim.x + threadIdx.x;
  int row = gid >> 3;       // 8 lanes per row
  int d8  = gid & 7;        // uint4 index (8 bf16 dims per lane)
  if (row >= N) return;
  int beg = rowptr[row], end = rowptr[row + 1];
  float a0 = 0.f, a1 = 0.f, a2 = 0.f, a3 = 0.f;
  float a4 = 0.f, a5 = 0.f, a6 = 0.f, a7 = 0.f;
  for (int k = beg; k < end; ++k) {
    float2 p = cpack[k];            // broadcast within the 8-lane group
    int   c = __float_as_int(p.x);
    float vv = p.y;
    uint4 q = ein[(size_t)c * 8 + d8];
    a0 = fmaf(vv, bflo(q.x), a0); a1 = fmaf(vv, bfhi(q.x), a1);
    a2 = fmaf(vv, bflo(q.y), a2); a3 = fmaf(vv, bfhi(q.y), a3);
    a4 = fmaf(vv, bflo(q.z), a4); a5 = fmaf(vv, bfhi(q.z), a5);
    a6 = fmaf(vv, bflo(q.w), a6); a7 = fmaf(vv, bfhi(q.w), a7);
  }
  eout[(size_t)row * 8 + d8] = make_uint4(bfpack(a0, a1), bfpack(a2, a3),
                                          bfpack(a4, a5), bfpack(a6, a7));
}

// fused: hop-0 (f32 exact) + hop-1/2 (bf16) + on-the-fly hop-3 + sigmoid/softmax dot
__global__ void k_final(const float* __restrict__ ut, const float* __restrict__ it,
                        const unsigned short* __restrict__ emb1,
                        const unsigned short* __restrict__ emb2,
                        const int* __restrict__ rowptr, const float2* __restrict__ cpack,
                        const int* __restrict__ users, const int* __restrict__ items,
                        const float* __restrict__ xij, const float* __restrict__ xtab,
                        float* __restrict__ out, int B, int NU) {
  int w = (blockIdx.x * blockDim.x + threadIdx.x) >> 6;
  int lane = threadIdx.x & 63;
  if (w >= B) return;
  int u = users[w];
  int v = NU + items[w];

  float accu = ut[(size_t)u * D + lane] + bf2f(emb1[(size_t)u * D + lane])
             + bf2f(emb2[(size_t)u * D + lane]);
  {
    int beg = rowptr[u], end = rowptr[u + 1];
    for (int k = beg; k < end; ++k) {
      float2 p = cpack[k];
      int c = __float_as_int(p.x);
      accu = fmaf(p.y, bf2f(emb2[(size_t)c * D + lane]), accu);
    }
  }
  float accv = it[(size_t)(v - NU) * D + lane] + bf2f(emb1[(size_t)v * D + lane])
             + bf2f(emb2[(size_t)v * D + lane]);
  {
    int beg = rowptr[v], end = rowptr[v + 1];
    for (int k = beg; k < end; ++k) {
      float2 p = cpack[k];
      int c = __float_as_int(p.x);
      accv = fmaf(p.y, bf2f(emb2[(size_t)c * D + lane]), accv);
    }
  }

  float ue = accu * 0.25f;   // /(L+1)
  float ie = accv * 0.25f;
  float xs = xij[w] - 0.3f;
  float xe = (lane < 8) ? xtab[lane] * xs : 0.f;

  float m = (lane < 8) ? fmaxf(ie, xe) : ie;
  for (int off = 32; off; off >>= 1) m = fmaxf(m, __shfl_xor(m, off));
  float e1 = expf(ie - m);
  float e2 = (lane < 8) ? expf(xe - m) : 0.f;
  float s = e1 + e2;
  for (int off = 32; off; off >>= 1) s += __shfl_xor(s, off);
  float inv = 1.f / s;

  float sig1 = 1.f / (1.f + expf(-ue));
  float term = sig1 * e1 * inv;
  if (lane < 8) {
    float sig2 = 1.f / (1.f + expf(-xe));
    term += sig2 * e2 * inv;
  }
  for (int off = 32; off; off >>= 1) term += __shfl_xor(term, off);
  if (lane == 0) out[w] = term;
}

extern "C" void kernel_launch(void* const* d_in, const int* in_sizes, int n_in,
                              void* d_out, int out_size, void* d_ws, size_t ws_size,
                              hipStream_t stream) {
  const int*   users = (const int*)d_in[0];
  const int*   items = (const int*)d_in[1];
  const float* xij   = (const float*)d_in[2];
  const float* utab  = (const float*)d_in[3];
  const float* itab  = (const float*)d_in[4];
  const float* xtab  = (const float*)d_in[5];
  const int*   erow  = (const int*)d_in[6];
  const int*   ecol  = (const int*)d_in[7];
  const float* evalp = (const float*)d_in[8];
  float* out = (float*)d_out;

  int B  = in_sizes[0];
  int NU = in_sizes[3] / D;
  int NI = in_sizes[4] / D;
  int N  = NU + NI;
  int E  = in_sizes[6];
  int RPB = (N + NB - 1) / NB;   // rows per bucket (587 for N=150000)

  char* ws = (char*)d_ws;
  size_t off = 0;
  auto carve = [&](size_t bytes) {
    void* p = ws + off;
    off += (bytes + 255) & ~(size_t)255;
    return p;
  };
  uint2*  embh0  = (uint2*)carve((size_t)N * D * 2);   // bf16 packed
  uint2*  embh1  = (uint2*)carve((size_t)N * D * 2);
  uint2*  embh2  = (uint2*)carve((size_t)N * D * 2);
  int*    rowptr = (int*)carve((size_t)(N + 1) * 4);
  int*    bhist  = (int*)carve((size_t)NB * 4);
  int*    bfill  = (int*)carve((size_t)NB * 4);
  int*    bbase  = (int*)carve((size_t)(NB + 1) * 4);
  int2*   binned = (int2*)carve((size_t)E * 8);
  float2* cpack  = (float2*)carve((size_t)E * 8);
  (void)ws_size; (void)n_in; (void)out_size;

  int ablocks = (E + PA_EDGES - 1) / PA_EDGES;

  // --- CSR build via two-pass binned counting sort ---
  hipLaunchKernelGGL(k_zero, dim3((2 * NB + 255) / 256), dim3(256), 0, stream,
                     bhist, 2 * NB);   // bhist + bfill (adjacent carves)
  hipLaunchKernelGGL(k_bhist, dim3(ablocks), dim3(PA_T), 0, stream, erow, bhist, E, RPB);
  hipLaunchKernelGGL(k_bscan, dim3(1), dim3(NB), 0, stream, bhist, bbase, E);
  hipLaunchKernelGGL(k_binA, dim3(ablocks), dim3(PA_T), 0, stream,
                     erow, ecol, evalp, bbase, bfill, binned, E, RPB);
  hipLaunchKernelGGL(k_binB, dim3(NB), dim3(PB_T), 0, stream,
                     binned, bbase, rowptr, cpack, N, E, RPB);

  // --- tables -> bf16 emb0 ---
  int tot16 = N * 16, nu16 = NU * 16;
  hipLaunchKernelGGL(k_cvt, dim3((tot16 + 255) / 256), dim3(256), 0, stream,
                     (const float4*)utab, (const float4*)itab, embh0, nu16, tot16);

  // --- hops 1,2 full (bf16); hop 3 fused into final ---
  hipLaunchKernelGGL(k_prop, dim3((N * 8 + 255) / 256), dim3(256), 0, stream,
                     (const uint4*)embh0, (uint4*)embh1, rowptr, cpack, N);
  hipLaunchKernelGGL(k_prop, dim3((N * 8 + 255) / 256), dim3(256), 0, stream,
                     (const uint4*)embh1, (uint4*)embh2, rowptr, cpack, N);

  hipLaunchKernelGGL(k_final, dim3((B * 64 + 255) / 256), dim3(256), 0, stream,
                     utab, itab, (const unsigned short*)embh1,
                     (const unsigned short*)embh2, rowptr, cpack,
                     users, items, xij, xtab, out, B, NU);
}